// Round 1
// baseline (55400.403 us; speedup 1.0000x reference)
//
#include <hip/hip_runtime.h>

// ---- model constants ----
#define DEM   768
#define SEQL  65
#define NHEAD 12
#define HDIM  64
#define NHID  3072
#define NEXP  8
#define NBATCH 256
#define STOK  (NBATCH*SEQL)   // 16640
#define CAPC  2600            // int(1.25 * 16640 / 8)
#define NCLS  1000
#define NLAY  8

// ============================================================
// Generic fp32 GEMM: C[M,N] = A[M,K] @ W[K,N] (+bias) (opt relu)
// A row stride = lda (for strided row gather, e.g. CLS tokens).
// 64x64 tile, BK=16, 256 threads, 4x4 micro-tile per thread.
// Requires K % 16 == 0.
// ============================================================
__global__ __launch_bounds__(256) void gemm_kernel(
    const float* __restrict__ A, const float* __restrict__ W,
    const float* __restrict__ bias, float* __restrict__ C,
    int M, int N, int K, int lda, int relu) {
  __shared__ float As[16][65];   // [k][m]
  __shared__ float Ws[16][65];   // [k][n]
  int tid = threadIdx.x;
  int bm = blockIdx.y * 64, bn = blockIdx.x * 64;
  int tx = tid & 15, ty = tid >> 4;
  float acc[4][4] = {};
  for (int k0 = 0; k0 < K; k0 += 16) {
    #pragma unroll
    for (int i = 0; i < 4; i++) {
      int idx = i * 256 + tid;
      int r = idx >> 4, c = idx & 15;
      int gr = bm + r;
      As[c][r] = (gr < M) ? A[(size_t)gr * lda + k0 + c] : 0.f;
    }
    #pragma unroll
    for (int i = 0; i < 4; i++) {
      int idx = i * 256 + tid;
      int r = idx >> 6, c = idx & 63;
      int gc = bn + c;
      Ws[r][c] = (gc < N) ? W[(size_t)(k0 + r) * N + gc] : 0.f;
    }
    __syncthreads();
    #pragma unroll
    for (int kk = 0; kk < 16; kk++) {
      float a[4], w[4];
      #pragma unroll
      for (int i = 0; i < 4; i++) a[i] = As[kk][ty * 4 + i];
      #pragma unroll
      for (int j = 0; j < 4; j++) w[j] = Ws[kk][tx * 4 + j];
      #pragma unroll
      for (int i = 0; i < 4; i++)
        #pragma unroll
        for (int j = 0; j < 4; j++) acc[i][j] += a[i] * w[j];
    }
    __syncthreads();
  }
  #pragma unroll
  for (int i = 0; i < 4; i++) {
    int gr = bm + ty * 4 + i;
    if (gr >= M) continue;
    #pragma unroll
    for (int j = 0; j < 4; j++) {
      int gc = bn + tx * 4 + j;
      if (gc >= N) continue;
      float v = acc[i][j];
      if (bias) v += bias[gc];
      if (relu) v = fmaxf(v, 0.f);
      C[(size_t)gr * N + gc] = v;
    }
  }
}

// ============================================================
// Patch embed + cls + pos:  h[B,65,768]
// ============================================================
__global__ __launch_bounds__(256) void patch_kernel(
    const float* __restrict__ x, const float* __restrict__ pw,
    const float* __restrict__ pb, const float* __restrict__ cls,
    const float* __restrict__ pos, float* __restrict__ h) {
  size_t tid = (size_t)blockIdx.x * 256 + threadIdx.x;
  const size_t total = (size_t)NBATCH * SEQL * DEM;
  if (tid >= total) return;
  int d = (int)(tid % DEM);
  int t = (int)((tid / DEM) % SEQL);
  int b = (int)(tid / ((size_t)DEM * SEQL));
  float v;
  if (t == 0) {
    v = cls[d] + pos[d];
  } else {
    int tt = t - 1, pi = tt >> 3, pj = tt & 7;
    float acc = pb[d];
    const float* xb = x + (size_t)b * 3072;
    #pragma unroll
    for (int ch = 0; ch < 3; ch++)
      #pragma unroll
      for (int r = 0; r < 4; r++)
        #pragma unroll
        for (int s = 0; s < 4; s++)
          acc += xb[ch * 1024 + (pi * 4 + r) * 32 + (pj * 4 + s)]
               * pw[(size_t)(ch * 16 + r * 4 + s) * DEM + d];
    v = acc + pos[(size_t)t * DEM + d];
  }
  h[tid] = v;
}

// ============================================================
// Attention per (b, head). QKV buffer layout: [B*T, 2304],
// q at col h*64, k at 768+h*64, v at 1536+h*64.
// ============================================================
__global__ __launch_bounds__(256) void attn_kernel(
    const float* __restrict__ qkv, float* __restrict__ out) {
  int bh = blockIdx.x;
  int b = bh / NHEAD, hh = bh % NHEAD;
  __shared__ float qk[2][SEQL][HDIM + 1];  // q in [0], k in [1]; later v in [0]
  __shared__ float sc[SEQL][SEQL];
  int tid = threadIdx.x;
  const size_t base = (size_t)b * SEQL * 2304 + hh * HDIM;
  for (int idx = tid; idx < SEQL * HDIM; idx += 256) {
    int r = idx >> 6, c = idx & 63;
    size_t p = base + (size_t)r * 2304 + c;
    qk[0][r][c] = qkv[p];
    qk[1][r][c] = qkv[p + DEM];
  }
  __syncthreads();
  for (int idx = tid; idx < SEQL * SEQL; idx += 256) {
    int qi = idx / SEQL, ki = idx % SEQL;
    float s = 0.f;
    #pragma unroll
    for (int d = 0; d < HDIM; d++) s += qk[0][qi][d] * qk[1][ki][d];
    sc[qi][ki] = s * 0.125f;   // 1/sqrt(64)
  }
  __syncthreads();
  if (tid < SEQL) {
    float mx = -1e30f;
    for (int k = 0; k < SEQL; k++) mx = fmaxf(mx, sc[tid][k]);
    float sum = 0.f;
    for (int k = 0; k < SEQL; k++) { float e = __expf(sc[tid][k] - mx); sc[tid][k] = e; sum += e; }
    float inv = 1.f / sum;
    for (int k = 0; k < SEQL; k++) sc[tid][k] *= inv;
  }
  __syncthreads();
  // overwrite q slot with v
  for (int idx = tid; idx < SEQL * HDIM; idx += 256) {
    int r = idx >> 6, c = idx & 63;
    qk[0][r][c] = qkv[base + (size_t)r * 2304 + c + 2 * DEM];
  }
  __syncthreads();
  for (int idx = tid; idx < SEQL * HDIM; idx += 256) {
    int qi = idx >> 6, d = idx & 63;
    float o = 0.f;
    for (int k = 0; k < SEQL; k++) o += sc[qi][k] * qk[0][k][d];
    out[((size_t)b * SEQL + qi) * DEM + hh * HDIM + d] = o;
  }
}

// ============================================================
// h = LayerNorm(h + f) * g + b   (one block per token, D=768)
// ============================================================
__global__ __launch_bounds__(256) void add_ln_kernel(
    float* __restrict__ h, const float* __restrict__ f,
    const float* __restrict__ g, const float* __restrict__ b) {
  int t = blockIdx.x, tid = threadIdx.x;
  float* hr = h + (size_t)t * DEM;
  const float* fr = f + (size_t)t * DEM;
  float x[3];
  float s = 0.f;
  #pragma unroll
  for (int i = 0; i < 3; i++) { x[i] = hr[tid + i * 256] + fr[tid + i * 256]; s += x[i]; }
  __shared__ float red[256];
  red[tid] = s; __syncthreads();
  for (int o = 128; o > 0; o >>= 1) { if (tid < o) red[tid] += red[tid + o]; __syncthreads(); }
  float mean = red[0] / (float)DEM;
  __syncthreads();
  float vs = 0.f;
  #pragma unroll
  for (int i = 0; i < 3; i++) { float d = x[i] - mean; vs += d * d; }
  red[tid] = vs; __syncthreads();
  for (int o = 128; o > 0; o >>= 1) { if (tid < o) red[tid] += red[tid + o]; __syncthreads(); }
  float var = red[0] / (float)DEM;
  float rstd = rsqrtf(var + 1e-5f);
  #pragma unroll
  for (int i = 0; i < 3; i++) {
    int d = tid + i * 256;
    hr[d] = (x[i] - mean) * rstd * g[d] + b[d];
  }
}

// ============================================================
// MoE gating phase A: per token softmax(8) + top-2 argmax
// ============================================================
__global__ __launch_bounds__(256) void moe_phase_a(
    const float* __restrict__ logits, int* __restrict__ e1, int* __restrict__ e2,
    float* __restrict__ gv1, float* __restrict__ gv2) {
  int s = blockIdx.x * 256 + threadIdx.x;
  if (s >= STOK) return;
  const float* l = logits + (size_t)s * NEXP;
  float lv[NEXP];
  #pragma unroll
  for (int e = 0; e < NEXP; e++) lv[e] = l[e];
  float mx = lv[0];
  #pragma unroll
  for (int e = 1; e < NEXP; e++) mx = fmaxf(mx, lv[e]);
  float g[NEXP]; float sum = 0.f;
  #pragma unroll
  for (int e = 0; e < NEXP; e++) { g[e] = __expf(lv[e] - mx); sum += g[e]; }
  float inv = 1.f / sum;
  int b1 = 0; float bv = lv[0];
  #pragma unroll
  for (int e = 1; e < NEXP; e++) if (lv[e] > bv) { bv = lv[e]; b1 = e; }  // first max
  int b2 = -1; float bv2 = -1e30f;
  #pragma unroll
  for (int e = 0; e < NEXP; e++) if (e != b1 && lv[e] > bv2) { bv2 = lv[e]; b2 = e; }
  e1[s] = b1; e2[s] = b2;
  gv1[s] = g[b1] * inv; gv2[s] = g[b2] * inv;
}

// ============================================================
// MoE scan: single wave. p1 = per-expert running count of first
// choices; p2 continues from totals (= cumsum(m2)-1 + m1.sum(0)).
// S must be a multiple of 64 (16640 = 260*64).
// ============================================================
__global__ __launch_bounds__(64) void moe_scan(
    const int* __restrict__ e1, const int* __restrict__ e2,
    int* __restrict__ p1, int* __restrict__ p2) {
  __shared__ int cnt[NEXP];
  int lane = threadIdx.x;
  if (lane < NEXP) cnt[lane] = 0;
  __syncthreads();
  for (int base = 0; base < STOK; base += 64) {
    int my = e1[base + lane];
    unsigned long long mymask = 0;
    #pragma unroll
    for (int e = 0; e < NEXP; e++) {
      unsigned long long m = __ballot(my == e);
      if (my == e) mymask = m;
    }
    int rank = __popcll(mymask & ((1ull << lane) - 1ull));
    p1[base + lane] = cnt[my] + rank;
    __syncthreads();
    if (rank == 0) cnt[my] += __popcll(mymask);
    __syncthreads();
  }
  for (int base = 0; base < STOK; base += 64) {
    int my = e2[base + lane];
    unsigned long long mymask = 0;
    #pragma unroll
    for (int e = 0; e < NEXP; e++) {
      unsigned long long m = __ballot(my == e);
      if (my == e) mymask = m;
    }
    int rank = __popcll(mymask & ((1ull << lane) - 1ull));
    p2[base + lane] = cnt[my] + rank;
    __syncthreads();
    if (rank == 0) cnt[my] += __popcll(mymask);
    __syncthreads();
  }
}

// ============================================================
// MoE phase C: capacity mask, gate renorm, slot ids
// ============================================================
__global__ __launch_bounds__(256) void moe_phase_c(
    const int* __restrict__ e1, const int* __restrict__ e2,
    const int* __restrict__ p1, const int* __restrict__ p2,
    const float* __restrict__ gv1, const float* __restrict__ gv2,
    int* __restrict__ slot1, int* __restrict__ slot2,
    int* __restrict__ k1, int* __restrict__ k2,
    float* __restrict__ g1, float* __restrict__ g2) {
  int s = blockIdx.x * 256 + threadIdx.x;
  if (s >= STOK) return;
  int P1 = p1[s], P2 = p2[s];
  int K1 = (P1 < CAPC) ? 1 : 0, K2 = (P2 < CAPC) ? 1 : 0;
  float G1 = gv1[s] * (float)K1, G2 = gv2[s] * (float)K2;
  float denom = fmaxf(G1 + G2, 1e-9f);
  g1[s] = G1 / denom; g2[s] = G2 / denom;
  int c1 = P1 < CAPC - 1 ? P1 : CAPC - 1;
  int c2 = P2 < CAPC - 1 ? P2 : CAPC - 1;
  slot1[s] = e1[s] * CAPC + c1;
  slot2[s] = e2[s] * CAPC + c2;
  k1[s] = K1; k2[s] = K2;
}

__global__ __launch_bounds__(256) void zero_kernel(float* __restrict__ p, size_t n) {
  size_t i = (size_t)blockIdx.x * 256 + threadIdx.x;
  if (i < n) p[i] = 0.f;
}

__global__ __launch_bounds__(256) void moe_scatter(
    const float* __restrict__ h, const int* __restrict__ slot1,
    const int* __restrict__ slot2, const int* __restrict__ k1,
    const int* __restrict__ k2, float* __restrict__ buf) {
  int s = blockIdx.x, tid = threadIdx.x;
  const float* hr = h + (size_t)s * DEM;
  int s1 = slot1[s], s2 = slot2[s], K1 = k1[s], K2 = k2[s];
  #pragma unroll
  for (int i = 0; i < 3; i++) {
    int d = tid + i * 256;
    float v = hr[d];
    if (K1) buf[(size_t)s1 * DEM + d] = v;   // kept slots are unique -> plain store
    if (K2) buf[(size_t)s2 * DEM + d] = v;
  }
}

__global__ __launch_bounds__(256) void moe_combine(
    const float* __restrict__ oe, const int* __restrict__ slot1,
    const int* __restrict__ slot2, const float* __restrict__ g1,
    const float* __restrict__ g2, float* __restrict__ out) {
  int s = blockIdx.x, tid = threadIdx.x;
  int s1 = slot1[s], s2 = slot2[s];
  float G1 = g1[s], G2 = g2[s];
  #pragma unroll
  for (int i = 0; i < 3; i++) {
    int d = tid + i * 256;
    out[(size_t)s * DEM + d] = oe[(size_t)s1 * DEM + d] * G1 + oe[(size_t)s2 * DEM + d] * G2;
  }
}

// ============================================================
// Loss: per-sample logsumexp - logits[y], then sum
// ============================================================
__global__ __launch_bounds__(256) void loss_kernel(
    const float* __restrict__ logits, const int* __restrict__ y,
    float* __restrict__ losses) {
  int b = blockIdx.x, tid = threadIdx.x;
  const float* l = logits + (size_t)b * NCLS;
  __shared__ float red[256];
  float mx = -1e30f;
  for (int c = tid; c < NCLS; c += 256) mx = fmaxf(mx, l[c]);
  red[tid] = mx; __syncthreads();
  for (int o = 128; o > 0; o >>= 1) { if (tid < o) red[tid] = fmaxf(red[tid], red[tid + o]); __syncthreads(); }
  mx = red[0]; __syncthreads();
  float s = 0.f;
  for (int c = tid; c < NCLS; c += 256) s += __expf(l[c] - mx);
  red[tid] = s; __syncthreads();
  for (int o = 128; o > 0; o >>= 1) { if (tid < o) red[tid] += red[tid + o]; __syncthreads(); }
  if (tid == 0) losses[b] = logf(red[0]) + mx - l[y[b]];
}

__global__ __launch_bounds__(256) void loss_reduce(
    const float* __restrict__ losses, float* __restrict__ out) {
  __shared__ float red[256];
  int tid = threadIdx.x;
  red[tid] = losses[tid]; __syncthreads();
  for (int o = 128; o > 0; o >>= 1) { if (tid < o) red[tid] += red[tid + o]; __syncthreads(); }
  if (tid == 0) out[0] = red[0];
}

// ============================================================
// Host orchestration
// ============================================================
extern "C" void kernel_launch(void* const* d_in, const int* in_sizes, int n_in,
                              void* d_out, int out_size, void* d_ws, size_t ws_size,
                              hipStream_t stream) {
  const float* x       = (const float*)d_in[0];
  const int*   y       = (const int*)  d_in[1];
  const float* patch_w = (const float*)d_in[2];
  const float* patch_b = (const float*)d_in[3];
  const float* cls     = (const float*)d_in[4];
  const float* pos     = (const float*)d_in[5];
  const float* wqkv    = (const float*)d_in[6];
  const float* bqkv    = (const float*)d_in[7];
  const float* wo      = (const float*)d_in[8];
  const float* bo      = (const float*)d_in[9];
  const float* ln1g    = (const float*)d_in[10];
  const float* ln1b    = (const float*)d_in[11];
  const float* ln2g    = (const float*)d_in[12];
  const float* ln2b    = (const float*)d_in[13];
  const float* dw1     = (const float*)d_in[14];
  const float* db1     = (const float*)d_in[15];
  const float* dw2     = (const float*)d_in[16];
  const float* db2     = (const float*)d_in[17];
  const float* gate_w  = (const float*)d_in[18];
  const float* ew1     = (const float*)d_in[19];
  const float* eb1     = (const float*)d_in[20];
  const float* ew2     = (const float*)d_in[21];
  const float* eb2     = (const float*)d_in[22];
  const float* dec_w   = (const float*)d_in[23];
  const float* dec_b   = (const float*)d_in[24];
  float* out = (float*)d_out;

  // ---- workspace layout (floats) ----
  const size_t SZ_BIG0 = (size_t)STOK * NHID;        // 51,118,080 (qkv 38.3M / ffn hid / expert hid / dec logits)
  const size_t SZ_TOK  = (size_t)STOK * DEM;         // 12,779,520
  const size_t SZ_BUF  = (size_t)NEXP * CAPC * DEM;  // 15,974,400
  float* big0 = (float*)d_ws;
  float* big1 = big0 + SZ_BIG0;
  float* h    = big1 + SZ_TOK;
  float* buf  = h + SZ_TOK;
  float* oe   = buf + SZ_BUF;
  float* glog = oe + SZ_BUF;              // STOK*8
  float* gv1  = glog + (size_t)STOK * NEXP;
  float* gv2  = gv1 + STOK;
  float* g1   = gv2 + STOK;
  float* g2   = g1 + STOK;
  float* losses = g2 + STOK;              // 256
  int* iw   = (int*)(losses + 256);
  int* e1v  = iw;
  int* e2v  = e1v + STOK;
  int* p1v  = e2v + STOK;
  int* p2v  = p1v + STOK;
  int* sl1  = p2v + STOK;
  int* sl2  = sl1 + STOK;
  int* k1v  = sl2 + STOK;
  int* k2v  = k1v + STOK;

  auto gemm = [&](const float* A, const float* W, const float* bias, float* Cm,
                  int M, int N, int K, int lda, int relu) {
    dim3 grid((N + 63) / 64, (M + 63) / 64);
    gemm_kernel<<<grid, 256, 0, stream>>>(A, W, bias, Cm, M, N, K, lda, relu);
  };

  // patch embed + cls + pos
  {
    size_t total = (size_t)NBATCH * SEQL * DEM;
    patch_kernel<<<(unsigned)((total + 255) / 256), 256, 0, stream>>>(
        x, patch_w, patch_b, cls, pos, h);
  }

  int di = 0, mi = 0;
  for (int i = 0; i < NLAY; i++) {
    // MHA
    gemm(h, wqkv + (size_t)i * DEM * 3 * DEM, bqkv + (size_t)i * 3 * DEM, big0,
         STOK, 3 * DEM, DEM, DEM, 0);
    attn_kernel<<<NBATCH * NHEAD, 256, 0, stream>>>(big0, big1);
    gemm(big1, wo + (size_t)i * DEM * DEM, bo + (size_t)i * DEM, big0,
         STOK, DEM, DEM, DEM, 0);
    add_ln_kernel<<<STOK, 256, 0, stream>>>(h, big0, ln1g + (size_t)i * DEM, ln1b + (size_t)i * DEM);

    if (i % 2 == 0) {
      // dense FFN
      gemm(h, dw1 + (size_t)di * DEM * NHID, db1 + (size_t)di * NHID, big0,
           STOK, NHID, DEM, DEM, 1);
      gemm(big0, dw2 + (size_t)di * NHID * DEM, db2 + (size_t)di * DEM, big1,
           STOK, DEM, NHID, NHID, 0);
      di++;
    } else {
      // MoE FFN
      gemm(h, gate_w + (size_t)mi * DEM * NEXP, nullptr, glog,
           STOK, NEXP, DEM, DEM, 0);
      moe_phase_a<<<(STOK + 255) / 256, 256, 0, stream>>>(glog, e1v, e2v, gv1, gv2);
      moe_scan<<<1, 64, 0, stream>>>(e1v, e2v, p1v, p2v);
      moe_phase_c<<<(STOK + 255) / 256, 256, 0, stream>>>(
          e1v, e2v, p1v, p2v, gv1, gv2, sl1, sl2, k1v, k2v, g1, g2);
      zero_kernel<<<(unsigned)((SZ_BUF + 255) / 256), 256, 0, stream>>>(buf, SZ_BUF);
      moe_scatter<<<STOK, 256, 0, stream>>>(h, sl1, sl2, k1v, k2v, buf);
      for (int e = 0; e < NEXP; e++) {
        const float* w1e = ew1 + ((size_t)mi * NEXP + e) * DEM * NHID;
        const float* b1e = eb1 + ((size_t)mi * NEXP + e) * NHID;
        const float* w2e = ew2 + ((size_t)mi * NEXP + e) * NHID * DEM;
        const float* b2e = eb2 + ((size_t)mi * NEXP + e) * DEM;
        gemm(buf + (size_t)e * CAPC * DEM, w1e, b1e, big0 + (size_t)e * CAPC * NHID,
             CAPC, NHID, DEM, DEM, 1);
        gemm(big0 + (size_t)e * CAPC * NHID, w2e, b2e, oe + (size_t)e * CAPC * DEM,
             CAPC, DEM, NHID, NHID, 0);
      }
      moe_combine<<<STOK, 256, 0, stream>>>(oe, sl1, sl2, g1, g2, big1);
      mi++;
    }
    add_ln_kernel<<<STOK, 256, 0, stream>>>(h, big1, ln2g + (size_t)i * DEM, ln2b + (size_t)i * DEM);
  }

  // decoder on CLS tokens (row stride 65*768) + loss
  gemm(h, dec_w, dec_b, big0, NBATCH, NCLS, DEM, SEQL * DEM, 0);
  loss_kernel<<<NBATCH, 256, 0, stream>>>(big0, y, losses);
  loss_reduce<<<1, 256, 0, stream>>>(losses, out);
}

// Round 2
// 8962.157 us; speedup vs baseline: 6.1816x; 6.1816x over previous
//
#include <hip/hip_runtime.h>

// ---- model constants ----
#define DEM   768
#define SEQL  65
#define NHEAD 12
#define HDIM  64
#define NHID  3072
#define NEXP  8
#define NBATCH 256
#define STOK  (NBATCH*SEQL)   // 16640 = 130*128
#define CAPC  2600            // int(1.25 * 16640 / 8)
#define CAPP  2688            // padded to 21*128 for MFMA tiles
#define NCLS  1000
#define NLAY  8

typedef unsigned short u16;
typedef unsigned int   u32;
typedef __attribute__((ext_vector_type(8))) short bf16x8;
typedef __attribute__((ext_vector_type(4))) float f32x4;

__device__ inline u16 f2b(float f) {
  u32 u = __float_as_uint(f);
  u += 0x7fffu + ((u >> 16) & 1u);   // round-to-nearest-even
  return (u16)(u >> 16);
}
__device__ inline float b2f(u16 v) { return __uint_as_float(((u32)v) << 16); }

// ============================================================
// bf16 MFMA GEMM: C[M,N] = A[M,K] @ Wt[N,K]^T (+bias)(relu)(bf16 out)
// Requires M%128==0, N%128==0, K%32==0. Batched via blockIdx.z.
// m97-style: 128x128 tile, BK=32, global_load_lds w=16, 2-barrier K-loop.
// ============================================================
__global__ __launch_bounds__(256) void gemm_bf16(
    const u16* __restrict__ A, size_t sA,
    const u16* __restrict__ Wt, size_t sW,
    const float* __restrict__ bias, size_t sB,
    void* __restrict__ Cv, size_t sC,
    int M, int N, int K, int relu, int obf) {
  __shared__ u16 As[128 * 32];
  __shared__ u16 Bs[128 * 32];
  const int z = blockIdx.z;
  A  += (size_t)z * sA;
  Wt += (size_t)z * sW;
  const float* bz = bias ? bias + (size_t)z * sB : nullptr;
  const int bm = blockIdx.y * 128, bn = blockIdx.x * 128;
  const int tid = threadIdx.x;
  const int lane = tid & 63, w = tid >> 6;
  const int wm = (w >> 1) * 64, wn = (w & 1) * 64;
  const int lr = lane >> 2, lc = lane & 3;

  // staging: wave w covers rows [w*32, w*32+32) of both tiles, 2 instrs each
  const u16* a0 = A  + (size_t)(bm + w * 32 + lr) * K + lc * 8;
  const u16* a1 = a0 + (size_t)16 * K;
  const u16* b0 = Wt + (size_t)(bn + w * 32 + lr) * K + lc * 8;
  const u16* b1 = b0 + (size_t)16 * K;
  u16* da0 = &As[(w * 32) * 32];
  u16* da1 = &As[(w * 32 + 16) * 32];
  u16* db0 = &Bs[(w * 32) * 32];
  u16* db1 = &Bs[(w * 32 + 16) * 32];

  f32x4 acc[4][4];
  #pragma unroll
  for (int i = 0; i < 4; i++)
    #pragma unroll
    for (int j = 0; j < 4; j++) acc[i][j] = (f32x4){0.f, 0.f, 0.f, 0.f};

  const int ar = lane & 15;          // fragment row within 16
  const int ac = (lane >> 4) * 8;    // k-chunk within 32

  for (int k0 = 0; k0 < K; k0 += 32) {
    __builtin_amdgcn_global_load_lds(
        (const __attribute__((address_space(1))) void*)(a0 + k0),
        (__attribute__((address_space(3))) void*)da0, 16, 0, 0);
    __builtin_amdgcn_global_load_lds(
        (const __attribute__((address_space(1))) void*)(a1 + k0),
        (__attribute__((address_space(3))) void*)da1, 16, 0, 0);
    __builtin_amdgcn_global_load_lds(
        (const __attribute__((address_space(1))) void*)(b0 + k0),
        (__attribute__((address_space(3))) void*)db0, 16, 0, 0);
    __builtin_amdgcn_global_load_lds(
        (const __attribute__((address_space(1))) void*)(b1 + k0),
        (__attribute__((address_space(3))) void*)db1, 16, 0, 0);
    __syncthreads();
    bf16x8 af[4], bfr[4];
    #pragma unroll
    for (int t = 0; t < 4; t++) {
      af[t]  = *(const bf16x8*)&As[(wm + t * 16 + ar) * 32 + ac];
      bfr[t] = *(const bf16x8*)&Bs[(wn + t * 16 + ar) * 32 + ac];
    }
    #pragma unroll
    for (int i = 0; i < 4; i++)
      #pragma unroll
      for (int j = 0; j < 4; j++)
        acc[i][j] = __builtin_amdgcn_mfma_f32_16x16x32_bf16(af[i], bfr[j], acc[i][j], 0, 0, 0);
    __syncthreads();
  }

  u16*   Cb = (u16*)Cv + (size_t)z * sC;
  float* Cf = (float*)Cv + (size_t)z * sC;
  #pragma unroll
  for (int i = 0; i < 4; i++) {
    int row0 = bm + wm + i * 16 + (lane >> 4) * 4;
    #pragma unroll
    for (int j = 0; j < 4; j++) {
      int col = bn + wn + j * 16 + (lane & 15);
      float bv = bz ? bz[col] : 0.f;
      #pragma unroll
      for (int r = 0; r < 4; r++) {
        float v = acc[i][j][r] + bv;
        if (relu) v = fmaxf(v, 0.f);
        size_t off = (size_t)(row0 + r) * N + col;
        if (obf) Cb[off] = f2b(v);
        else     Cf[off] = v;
      }
    }
  }
}

// ============================================================
// fp32 GEMM (kept for gate N=8 and decoder N=1000)
// ============================================================
__global__ __launch_bounds__(256) void gemm_kernel(
    const float* __restrict__ A, const float* __restrict__ W,
    const float* __restrict__ bias, float* __restrict__ C,
    int M, int N, int K, int lda, int relu) {
  __shared__ float As[16][65];
  __shared__ float Ws[16][65];
  int tid = threadIdx.x;
  int bm = blockIdx.y * 64, bn = blockIdx.x * 64;
  int tx = tid & 15, ty = tid >> 4;
  float acc[4][4] = {};
  for (int k0 = 0; k0 < K; k0 += 16) {
    #pragma unroll
    for (int i = 0; i < 4; i++) {
      int idx = i * 256 + tid;
      int r = idx >> 4, c = idx & 15;
      int gr = bm + r;
      As[c][r] = (gr < M) ? A[(size_t)gr * lda + k0 + c] : 0.f;
    }
    #pragma unroll
    for (int i = 0; i < 4; i++) {
      int idx = i * 256 + tid;
      int r = idx >> 6, c = idx & 63;
      int gc = bn + c;
      Ws[r][c] = (gc < N) ? W[(size_t)(k0 + r) * N + gc] : 0.f;
    }
    __syncthreads();
    #pragma unroll
    for (int kk = 0; kk < 16; kk++) {
      float a[4], wv[4];
      #pragma unroll
      for (int i = 0; i < 4; i++) a[i] = As[kk][ty * 4 + i];
      #pragma unroll
      for (int j = 0; j < 4; j++) wv[j] = Ws[kk][tx * 4 + j];
      #pragma unroll
      for (int i = 0; i < 4; i++)
        #pragma unroll
        for (int j = 0; j < 4; j++) acc[i][j] += a[i] * wv[j];
    }
    __syncthreads();
  }
  #pragma unroll
  for (int i = 0; i < 4; i++) {
    int gr = bm + ty * 4 + i;
    if (gr >= M) continue;
    #pragma unroll
    for (int j = 0; j < 4; j++) {
      int gc = bn + tx * 4 + j;
      if (gc >= N) continue;
      float v = acc[i][j];
      if (bias) v += bias[gc];
      if (relu) v = fmaxf(v, 0.f);
      C[(size_t)gr * N + gc] = v;
    }
  }
}

// ============================================================
// Transpose + fp32->bf16: in [K][N] fp32 -> out [N][K] bf16 (batched z)
// K,N multiples of 32.
// ============================================================
__global__ __launch_bounds__(256) void transpose_cvt(
    const float* __restrict__ in, u16* __restrict__ out, int K, int N) {
  __shared__ float tile[32][33];
  int bz = blockIdx.z;
  in  += (size_t)bz * K * N;
  out += (size_t)bz * K * N;
  int n0 = blockIdx.x * 32, k0 = blockIdx.y * 32;
  int tx = threadIdx.x & 31, ty = threadIdx.x >> 5;
  #pragma unroll
  for (int i = 0; i < 4; i++)
    tile[ty + i * 8][tx] = in[(size_t)(k0 + ty + i * 8) * N + n0 + tx];
  __syncthreads();
  #pragma unroll
  for (int i = 0; i < 4; i++)
    out[(size_t)(n0 + ty + i * 8) * K + k0 + tx] = f2b(tile[tx][ty + i * 8]);
}

// fp32 -> bf16 elementwise (n % 4 == 0)
__global__ __launch_bounds__(256) void cvt_bf16(
    const float* __restrict__ in, u16* __restrict__ out, size_t n4) {
  size_t i = (size_t)blockIdx.x * 256 + threadIdx.x;
  if (i >= n4) return;
  float4 v = *(const float4*)(in + i * 4);
  u32 lo = (u32)f2b(v.x) | ((u32)f2b(v.y) << 16);
  u32 hi = (u32)f2b(v.z) | ((u32)f2b(v.w) << 16);
  *(uint2*)(out + i * 4) = make_uint2(lo, hi);
}

__global__ __launch_bounds__(256) void zero_u32(u32* __restrict__ p, size_t n) {
  size_t i = (size_t)blockIdx.x * 256 + threadIdx.x;
  if (i < n) p[i] = 0u;
}

// ============================================================
// Patch embed + cls + pos:  h[B,65,768] fp32
// ============================================================
__global__ __launch_bounds__(256) void patch_kernel(
    const float* __restrict__ x, const float* __restrict__ pw,
    const float* __restrict__ pb, const float* __restrict__ cls,
    const float* __restrict__ pos, float* __restrict__ h) {
  size_t tid = (size_t)blockIdx.x * 256 + threadIdx.x;
  const size_t total = (size_t)NBATCH * SEQL * DEM;
  if (tid >= total) return;
  int d = (int)(tid % DEM);
  int t = (int)((tid / DEM) % SEQL);
  int b = (int)(tid / ((size_t)DEM * SEQL));
  float v;
  if (t == 0) {
    v = cls[d] + pos[d];
  } else {
    int tt = t - 1, pi = tt >> 3, pj = tt & 7;
    float acc = pb[d];
    const float* xb = x + (size_t)b * 3072;
    #pragma unroll
    for (int ch = 0; ch < 3; ch++)
      #pragma unroll
      for (int r = 0; r < 4; r++)
        #pragma unroll
        for (int s = 0; s < 4; s++)
          acc += xb[ch * 1024 + (pi * 4 + r) * 32 + (pj * 4 + s)]
               * pw[(size_t)(ch * 16 + r * 4 + s) * DEM + d];
    v = acc + pos[(size_t)t * DEM + d];
  }
  h[tid] = v;
}

// ============================================================
// Attention per (b, head). qkv bf16 [B*T, 2304]; out bf16 [B*T, 768]
// ============================================================
__global__ __launch_bounds__(256) void attn_kernel(
    const u16* __restrict__ qkv, u16* __restrict__ out) {
  int bh = blockIdx.x;
  int b = bh / NHEAD, hh = bh % NHEAD;
  __shared__ float qk[2][SEQL][HDIM + 1];
  __shared__ float sc[SEQL][SEQL];
  int tid = threadIdx.x;
  const size_t base = (size_t)b * SEQL * 2304 + hh * HDIM;
  for (int idx = tid; idx < SEQL * HDIM; idx += 256) {
    int r = idx >> 6, c = idx & 63;
    size_t p = base + (size_t)r * 2304 + c;
    qk[0][r][c] = b2f(qkv[p]);
    qk[1][r][c] = b2f(qkv[p + DEM]);
  }
  __syncthreads();
  for (int idx = tid; idx < SEQL * SEQL; idx += 256) {
    int qi = idx / SEQL, ki = idx % SEQL;
    float s = 0.f;
    #pragma unroll
    for (int d = 0; d < HDIM; d++) s += qk[0][qi][d] * qk[1][ki][d];
    sc[qi][ki] = s * 0.125f;
  }
  __syncthreads();
  if (tid < SEQL) {
    float mx = -1e30f;
    for (int k = 0; k < SEQL; k++) mx = fmaxf(mx, sc[tid][k]);
    float sum = 0.f;
    for (int k = 0; k < SEQL; k++) { float e = __expf(sc[tid][k] - mx); sc[tid][k] = e; sum += e; }
    float inv = 1.f / sum;
    for (int k = 0; k < SEQL; k++) sc[tid][k] *= inv;
  }
  __syncthreads();
  for (int idx = tid; idx < SEQL * HDIM; idx += 256) {
    int r = idx >> 6, c = idx & 63;
    qk[0][r][c] = b2f(qkv[base + (size_t)r * 2304 + c + 2 * DEM]);
  }
  __syncthreads();
  for (int idx = tid; idx < SEQL * HDIM; idx += 256) {
    int qi = idx >> 6, d = idx & 63;
    float o = 0.f;
    for (int k = 0; k < SEQL; k++) o += sc[qi][k] * qk[0][k][d];
    out[((size_t)b * SEQL + qi) * DEM + hh * HDIM + d] = f2b(o);
  }
}

// ============================================================
// h = LayerNorm(h + f) * g + b   (one block per token)
// ============================================================
__global__ __launch_bounds__(256) void add_ln_kernel(
    float* __restrict__ h, const float* __restrict__ f,
    const float* __restrict__ g, const float* __restrict__ b) {
  int t = blockIdx.x, tid = threadIdx.x;
  float* hr = h + (size_t)t * DEM;
  const float* fr = f + (size_t)t * DEM;
  float x[3];
  float s = 0.f;
  #pragma unroll
  for (int i = 0; i < 3; i++) { x[i] = hr[tid + i * 256] + fr[tid + i * 256]; s += x[i]; }
  __shared__ float red[256];
  red[tid] = s; __syncthreads();
  for (int o = 128; o > 0; o >>= 1) { if (tid < o) red[tid] += red[tid + o]; __syncthreads(); }
  float mean = red[0] / (float)DEM;
  __syncthreads();
  float vs = 0.f;
  #pragma unroll
  for (int i = 0; i < 3; i++) { float d = x[i] - mean; vs += d * d; }
  red[tid] = vs; __syncthreads();
  for (int o = 128; o > 0; o >>= 1) { if (tid < o) red[tid] += red[tid + o]; __syncthreads(); }
  float var = red[0] / (float)DEM;
  float rstd = rsqrtf(var + 1e-5f);
  #pragma unroll
  for (int i = 0; i < 3; i++) {
    int d = tid + i * 256;
    hr[d] = (x[i] - mean) * rstd * g[d] + b[d];
  }
}

// ============================================================
// MoE gating
// ============================================================
__global__ __launch_bounds__(256) void moe_phase_a(
    const float* __restrict__ logits, int* __restrict__ e1, int* __restrict__ e2,
    float* __restrict__ gv1, float* __restrict__ gv2) {
  int s = blockIdx.x * 256 + threadIdx.x;
  if (s >= STOK) return;
  const float* l = logits + (size_t)s * NEXP;
  float lv[NEXP];
  #pragma unroll
  for (int e = 0; e < NEXP; e++) lv[e] = l[e];
  float mx = lv[0];
  #pragma unroll
  for (int e = 1; e < NEXP; e++) mx = fmaxf(mx, lv[e]);
  float g[NEXP]; float sum = 0.f;
  #pragma unroll
  for (int e = 0; e < NEXP; e++) { g[e] = __expf(lv[e] - mx); sum += g[e]; }
  float inv = 1.f / sum;
  int b1 = 0; float bv = lv[0];
  #pragma unroll
  for (int e = 1; e < NEXP; e++) if (lv[e] > bv) { bv = lv[e]; b1 = e; }
  int b2 = -1; float bv2 = -1e30f;
  #pragma unroll
  for (int e = 0; e < NEXP; e++) if (e != b1 && lv[e] > bv2) { bv2 = lv[e]; b2 = e; }
  e1[s] = b1; e2[s] = b2;
  gv1[s] = g[b1] * inv; gv2[s] = g[b2] * inv;
}

__global__ __launch_bounds__(64) void moe_scan(
    const int* __restrict__ e1, const int* __restrict__ e2,
    int* __restrict__ p1, int* __restrict__ p2) {
  __shared__ int cnt[NEXP];
  int lane = threadIdx.x;
  if (lane < NEXP) cnt[lane] = 0;
  __syncthreads();
  for (int base = 0; base < STOK; base += 64) {
    int my = e1[base + lane];
    unsigned long long mymask = 0;
    #pragma unroll
    for (int e = 0; e < NEXP; e++) {
      unsigned long long m = __ballot(my == e);
      if (my == e) mymask = m;
    }
    int rank = __popcll(mymask & ((1ull << lane) - 1ull));
    p1[base + lane] = cnt[my] + rank;
    __syncthreads();
    if (rank == 0) cnt[my] += __popcll(mymask);
    __syncthreads();
  }
  for (int base = 0; base < STOK; base += 64) {
    int my = e2[base + lane];
    unsigned long long mymask = 0;
    #pragma unroll
    for (int e = 0; e < NEXP; e++) {
      unsigned long long m = __ballot(my == e);
      if (my == e) mymask = m;
    }
    int rank = __popcll(mymask & ((1ull << lane) - 1ull));
    p2[base + lane] = cnt[my] + rank;
    __syncthreads();
    if (rank == 0) cnt[my] += __popcll(mymask);
    __syncthreads();
  }
}

__global__ __launch_bounds__(256) void moe_phase_c(
    const int* __restrict__ e1, const int* __restrict__ e2,
    const int* __restrict__ p1, const int* __restrict__ p2,
    const float* __restrict__ gv1, const float* __restrict__ gv2,
    int* __restrict__ slot1, int* __restrict__ slot2,
    int* __restrict__ k1, int* __restrict__ k2,
    float* __restrict__ g1, float* __restrict__ g2) {
  int s = blockIdx.x * 256 + threadIdx.x;
  if (s >= STOK) return;
  int P1 = p1[s], P2 = p2[s];
  int K1 = (P1 < CAPC) ? 1 : 0, K2 = (P2 < CAPC) ? 1 : 0;
  float G1 = gv1[s] * (float)K1, G2 = gv2[s] * (float)K2;
  float denom = fmaxf(G1 + G2, 1e-9f);
  g1[s] = G1 / denom; g2[s] = G2 / denom;
  int c1 = P1 < CAPC - 1 ? P1 : CAPC - 1;
  int c2 = P2 < CAPC - 1 ? P2 : CAPC - 1;
  slot1[s] = e1[s] * CAPP + c1;   // CAPP stride for padded buffers
  slot2[s] = e2[s] * CAPP + c2;
  k1[s] = K1; k2[s] = K2;
}

__global__ __launch_bounds__(256) void moe_scatter(
    const u16* __restrict__ hb, const int* __restrict__ slot1,
    const int* __restrict__ slot2, const int* __restrict__ k1,
    const int* __restrict__ k2, u16* __restrict__ ebuf) {
  int s = blockIdx.x, tid = threadIdx.x;
  const u16* hr = hb + (size_t)s * DEM;
  int s1 = slot1[s], s2 = slot2[s], K1 = k1[s], K2 = k2[s];
  #pragma unroll
  for (int i = 0; i < 3; i++) {
    int d = tid + i * 256;
    u16 v = hr[d];
    if (K1) ebuf[(size_t)s1 * DEM + d] = v;
    if (K2) ebuf[(size_t)s2 * DEM + d] = v;
  }
}

__global__ __launch_bounds__(256) void moe_combine(
    const float* __restrict__ oe, const int* __restrict__ slot1,
    const int* __restrict__ slot2, const float* __restrict__ g1,
    const float* __restrict__ g2, float* __restrict__ out) {
  int s = blockIdx.x, tid = threadIdx.x;
  int s1 = slot1[s], s2 = slot2[s];
  float G1 = g1[s], G2 = g2[s];
  #pragma unroll
  for (int i = 0; i < 3; i++) {
    int d = tid + i * 256;
    out[(size_t)s * DEM + d] = oe[(size_t)s1 * DEM + d] * G1 + oe[(size_t)s2 * DEM + d] * G2;
  }
}

// ============================================================
// Loss
// ============================================================
__global__ __launch_bounds__(256) void loss_kernel(
    const float* __restrict__ logits, const int* __restrict__ y,
    float* __restrict__ losses) {
  int b = blockIdx.x, tid = threadIdx.x;
  const float* l = logits + (size_t)b * NCLS;
  __shared__ float red[256];
  float mx = -1e30f;
  for (int c = tid; c < NCLS; c += 256) mx = fmaxf(mx, l[c]);
  red[tid] = mx; __syncthreads();
  for (int o = 128; o > 0; o >>= 1) { if (tid < o) red[tid] = fmaxf(red[tid], red[tid + o]); __syncthreads(); }
  mx = red[0]; __syncthreads();
  float s = 0.f;
  for (int c = tid; c < NCLS; c += 256) s += __expf(l[c] - mx);
  red[tid] = s; __syncthreads();
  for (int o = 128; o > 0; o >>= 1) { if (tid < o) red[tid] += red[tid + o]; __syncthreads(); }
  if (tid == 0) losses[b] = logf(red[0]) + mx - l[y[b]];
}

__global__ __launch_bounds__(256) void loss_reduce(
    const float* __restrict__ losses, float* __restrict__ out) {
  __shared__ float red[256];
  int tid = threadIdx.x;
  red[tid] = losses[tid]; __syncthreads();
  for (int o = 128; o > 0; o >>= 1) { if (tid < o) red[tid] += red[tid + o]; __syncthreads(); }
  if (tid == 0) out[0] = red[0];
}

// ============================================================
// Host orchestration
// ============================================================
extern "C" void kernel_launch(void* const* d_in, const int* in_sizes, int n_in,
                              void* d_out, int out_size, void* d_ws, size_t ws_size,
                              hipStream_t stream) {
  const float* x       = (const float*)d_in[0];
  const int*   y       = (const int*)  d_in[1];
  const float* patch_w = (const float*)d_in[2];
  const float* patch_b = (const float*)d_in[3];
  const float* cls     = (const float*)d_in[4];
  const float* pos     = (const float*)d_in[5];
  const float* wqkv    = (const float*)d_in[6];
  const float* bqkv    = (const float*)d_in[7];
  const float* wo      = (const float*)d_in[8];
  const float* bo      = (const float*)d_in[9];
  const float* ln1g    = (const float*)d_in[10];
  const float* ln1b    = (const float*)d_in[11];
  const float* ln2g    = (const float*)d_in[12];
  const float* ln2b    = (const float*)d_in[13];
  const float* dw1     = (const float*)d_in[14];
  const float* db1     = (const float*)d_in[15];
  const float* dw2     = (const float*)d_in[16];
  const float* db2     = (const float*)d_in[17];
  const float* gate_w  = (const float*)d_in[18];
  const float* ew1     = (const float*)d_in[19];
  const float* eb1     = (const float*)d_in[20];
  const float* ew2     = (const float*)d_in[21];
  const float* eb2     = (const float*)d_in[22];
  const float* dec_w   = (const float*)d_in[23];
  const float* dec_b   = (const float*)d_in[24];
  float* out = (float*)d_out;

  // ---- workspace layout (byte cursor, 256B aligned regions) ----
  char* cur = (char*)d_ws;
  auto alloc = [&](size_t bytes) -> char* {
    char* p = cur;
    cur += (bytes + 255) & ~(size_t)255;
    return p;
  };
  float* h    = (float*)alloc((size_t)STOK * DEM * 4);
  float* big1 = (float*)alloc((size_t)STOK * DEM * 4);           // f buffer (fp32)
  float* oe   = (float*)alloc((size_t)NEXP * CAPP * DEM * 4);    // expert out / dec logits
  float* glog = (float*)alloc((size_t)STOK * NEXP * 4);
  float* gv1  = (float*)alloc((size_t)STOK * 4);
  float* gv2  = (float*)alloc((size_t)STOK * 4);
  float* g1   = (float*)alloc((size_t)STOK * 4);
  float* g2   = (float*)alloc((size_t)STOK * 4);
  float* losses = (float*)alloc(256 * 4);
  int* e1v = (int*)alloc((size_t)STOK * 4);
  int* e2v = (int*)alloc((size_t)STOK * 4);
  int* p1v = (int*)alloc((size_t)STOK * 4);
  int* p2v = (int*)alloc((size_t)STOK * 4);
  int* sl1 = (int*)alloc((size_t)STOK * 4);
  int* sl2 = (int*)alloc((size_t)STOK * 4);
  int* k1v = (int*)alloc((size_t)STOK * 4);
  int* k2v = (int*)alloc((size_t)STOK * 4);
  u16* hb   = (u16*)alloc((size_t)STOK * DEM * 2);               // bf16 of h
  u16* ab   = (u16*)alloc((size_t)STOK * DEM * 2);               // bf16 attn out
  u16* ubuf = (u16*)alloc((size_t)NEXP * CAPP * NHID * 2);       // qkv bf16 / hidden bf16
  u16* wt   = (u16*)alloc((size_t)NEXP * NHID * DEM * 2);        // transposed weights bf16
  u16* ebuf = (u16*)alloc((size_t)NEXP * CAPP * DEM * 2);        // expert input bf16

  const size_t n4tok = (size_t)STOK * DEM / 4;

  auto gemmM = [&](const u16* A, size_t sA, const u16* W, size_t sW,
                   const float* bias, size_t sB, void* C, size_t sC,
                   int M, int N, int K, int relu, int obf, int batch) {
    dim3 grid(N / 128, M / 128, batch);
    gemm_bf16<<<grid, 256, 0, stream>>>(A, sA, W, sW, bias, sB, C, sC, M, N, K, relu, obf);
  };
  auto trans = [&](const float* in, u16* o, int K, int N, int batch) {
    dim3 grid(N / 32, K / 32, batch);
    transpose_cvt<<<grid, 256, 0, stream>>>(in, o, K, N);
  };
  auto cvt = [&](const float* in, u16* o) {
    cvt_bf16<<<(unsigned)((n4tok + 255) / 256), 256, 0, stream>>>(in, o, n4tok);
  };

  // patch embed
  {
    size_t total = (size_t)NBATCH * SEQL * DEM;
    patch_kernel<<<(unsigned)((total + 255) / 256), 256, 0, stream>>>(
        x, patch_w, patch_b, cls, pos, h);
  }

  int di = 0, mi = 0;
  for (int i = 0; i < NLAY; i++) {
    // ---- MHA ----
    cvt(h, hb);
    trans(wqkv + (size_t)i * DEM * 3 * DEM, wt, DEM, 3 * DEM, 1);
    gemmM(hb, 0, wt, 0, bqkv + (size_t)i * 3 * DEM, 0, ubuf, 0,
          STOK, 3 * DEM, DEM, 0, 1, 1);
    attn_kernel<<<NBATCH * NHEAD, 256, 0, stream>>>(ubuf, ab);
    trans(wo + (size_t)i * DEM * DEM, wt, DEM, DEM, 1);
    gemmM(ab, 0, wt, 0, bo + (size_t)i * DEM, 0, big1, 0,
          STOK, DEM, DEM, 0, 0, 1);
    add_ln_kernel<<<STOK, 256, 0, stream>>>(h, big1, ln1g + (size_t)i * DEM, ln1b + (size_t)i * DEM);
    cvt(h, hb);

    if (i % 2 == 0) {
      // ---- dense FFN ----
      trans(dw1 + (size_t)di * DEM * NHID, wt, DEM, NHID, 1);
      gemmM(hb, 0, wt, 0, db1 + (size_t)di * NHID, 0, ubuf, 0,
            STOK, NHID, DEM, 1, 1, 1);
      trans(dw2 + (size_t)di * NHID * DEM, wt, NHID, DEM, 1);
      gemmM(ubuf, 0, wt, 0, db2 + (size_t)di * DEM, 0, big1, 0,
            STOK, DEM, NHID, 0, 0, 1);
      di++;
    } else {
      // ---- MoE FFN ----
      {
        dim3 grid((NEXP + 63) / 64, (STOK + 63) / 64);
        gemm_kernel<<<grid, 256, 0, stream>>>(h, gate_w + (size_t)mi * DEM * NEXP,
                                              nullptr, glog, STOK, NEXP, DEM, DEM, 0);
      }
      moe_phase_a<<<(STOK + 255) / 256, 256, 0, stream>>>(glog, e1v, e2v, gv1, gv2);
      moe_scan<<<1, 64, 0, stream>>>(e1v, e2v, p1v, p2v);
      moe_phase_c<<<(STOK + 255) / 256, 256, 0, stream>>>(
          e1v, e2v, p1v, p2v, gv1, gv2, sl1, sl2, k1v, k2v, g1, g2);
      {
        size_t nz = (size_t)NEXP * CAPP * DEM / 2;  // u32 count
        zero_u32<<<(unsigned)((nz + 255) / 256), 256, 0, stream>>>((u32*)ebuf, nz);
      }
      moe_scatter<<<STOK, 256, 0, stream>>>(hb, sl1, sl2, k1v, k2v, ebuf);
      // expert FFN1 (batched over 8 experts)
      trans(ew1 + (size_t)mi * NEXP * DEM * NHID, wt, DEM, NHID, NEXP);
      gemmM(ebuf, (size_t)CAPP * DEM, wt, (size_t)NHID * DEM,
            eb1 + (size_t)mi * NEXP * NHID, NHID, ubuf, (size_t)CAPP * NHID,
            CAPP, NHID, DEM, 1, 1, NEXP);
      // expert FFN2
      trans(ew2 + (size_t)mi * NEXP * NHID * DEM, wt, NHID, DEM, NEXP);
      gemmM(ubuf, (size_t)CAPP * NHID, wt, (size_t)DEM * NHID,
            eb2 + (size_t)mi * NEXP * DEM, DEM, oe, (size_t)CAPP * DEM,
            CAPP, DEM, NHID, 0, 0, NEXP);
      moe_combine<<<STOK, 256, 0, stream>>>(oe, sl1, sl2, g1, g2, big1);
      mi++;
    }
    add_ln_kernel<<<STOK, 256, 0, stream>>>(h, big1, ln2g + (size_t)i * DEM, ln2b + (size_t)i * DEM);
  }

  // decoder on CLS tokens + loss (oe reused for logits)
  {
    dim3 grid((NCLS + 63) / 64, (NBATCH + 63) / 64);
    gemm_kernel<<<grid, 256, 0, stream>>>(h, dec_w, dec_b, oe,
                                          NBATCH, NCLS, DEM, SEQL * DEM, 0);
  }
  loss_kernel<<<NBATCH, 256, 0, stream>>>(oe, y, losses);
  loss_reduce<<<1, 256, 0, stream>>>(losses, out);
}

// Round 3
// 6368.531 us; speedup vs baseline: 8.6991x; 1.4073x over previous
//
#include <hip/hip_runtime.h>

// ---- model constants ----
#define DEM   768
#define SEQL  65
#define NHEAD 12
#define HDIM  64
#define NHID  3072
#define NEXP  8
#define NBATCH 256
#define STOK  (NBATCH*SEQL)   // 16640 = 130*128 = 65*256
#define CAPC  2600            // int(1.25 * 16640 / 8)
#define CAPP  2688            // padded to 21*128 for MFMA tiles
#define NCLS  1000
#define NLAY  8

typedef unsigned short u16;
typedef unsigned int   u32;
typedef __attribute__((ext_vector_type(8))) short bf16x8;
typedef __attribute__((ext_vector_type(4))) float f32x4;

__device__ inline u16 f2b(float f) {
  u32 u = __float_as_uint(f);
  u += 0x7fffu + ((u >> 16) & 1u);   // round-to-nearest-even
  return (u16)(u >> 16);
}
__device__ inline float b2f(u16 v) { return __uint_as_float(((u32)v) << 16); }

// ============================================================
// bf16 MFMA GEMM: C[M,N] = A[M,K] @ Wt[N,K]^T (+bias)(relu)(bf16 out)
// M%128==0, N%128==0, K%32==0. Batched via blockIdx.z. (m97 structure)
// ============================================================
__global__ __launch_bounds__(256) void gemm_bf16(
    const u16* __restrict__ A, size_t sA,
    const u16* __restrict__ Wt, size_t sW,
    const float* __restrict__ bias, size_t sB,
    void* __restrict__ Cv, size_t sC,
    int M, int N, int K, int relu, int obf) {
  __shared__ u16 As[128 * 32];
  __shared__ u16 Bs[128 * 32];
  const int z = blockIdx.z;
  A  += (size_t)z * sA;
  Wt += (size_t)z * sW;
  const float* bz = bias ? bias + (size_t)z * sB : nullptr;
  const int bm = blockIdx.y * 128, bn = blockIdx.x * 128;
  const int tid = threadIdx.x;
  const int lane = tid & 63, w = tid >> 6;
  const int wm = (w >> 1) * 64, wn = (w & 1) * 64;
  const int lr = lane >> 2, lc = lane & 3;

  const u16* a0 = A  + (size_t)(bm + w * 32 + lr) * K + lc * 8;
  const u16* a1 = a0 + (size_t)16 * K;
  const u16* b0 = Wt + (size_t)(bn + w * 32 + lr) * K + lc * 8;
  const u16* b1 = b0 + (size_t)16 * K;
  u16* da0 = &As[(w * 32) * 32];
  u16* da1 = &As[(w * 32 + 16) * 32];
  u16* db0 = &Bs[(w * 32) * 32];
  u16* db1 = &Bs[(w * 32 + 16) * 32];

  f32x4 acc[4][4];
  #pragma unroll
  for (int i = 0; i < 4; i++)
    #pragma unroll
    for (int j = 0; j < 4; j++) acc[i][j] = (f32x4){0.f, 0.f, 0.f, 0.f};

  const int ar = lane & 15;
  const int ac = (lane >> 4) * 8;

  for (int k0 = 0; k0 < K; k0 += 32) {
    __builtin_amdgcn_global_load_lds(
        (const __attribute__((address_space(1))) void*)(a0 + k0),
        (__attribute__((address_space(3))) void*)da0, 16, 0, 0);
    __builtin_amdgcn_global_load_lds(
        (const __attribute__((address_space(1))) void*)(a1 + k0),
        (__attribute__((address_space(3))) void*)da1, 16, 0, 0);
    __builtin_amdgcn_global_load_lds(
        (const __attribute__((address_space(1))) void*)(b0 + k0),
        (__attribute__((address_space(3))) void*)db0, 16, 0, 0);
    __builtin_amdgcn_global_load_lds(
        (const __attribute__((address_space(1))) void*)(b1 + k0),
        (__attribute__((address_space(3))) void*)db1, 16, 0, 0);
    __syncthreads();
    bf16x8 af[4], bfr[4];
    #pragma unroll
    for (int t = 0; t < 4; t++) {
      af[t]  = *(const bf16x8*)&As[(wm + t * 16 + ar) * 32 + ac];
      bfr[t] = *(const bf16x8*)&Bs[(wn + t * 16 + ar) * 32 + ac];
    }
    #pragma unroll
    for (int i = 0; i < 4; i++)
      #pragma unroll
      for (int j = 0; j < 4; j++)
        acc[i][j] = __builtin_amdgcn_mfma_f32_16x16x32_bf16(af[i], bfr[j], acc[i][j], 0, 0, 0);
    __syncthreads();
  }

  u16*   Cb = (u16*)Cv + (size_t)z * sC;
  float* Cf = (float*)Cv + (size_t)z * sC;
  #pragma unroll
  for (int i = 0; i < 4; i++) {
    int row0 = bm + wm + i * 16 + (lane >> 4) * 4;
    #pragma unroll
    for (int j = 0; j < 4; j++) {
      int col = bn + wn + j * 16 + (lane & 15);
      float bv = bz ? bz[col] : 0.f;
      #pragma unroll
      for (int r = 0; r < 4; r++) {
        float v = acc[i][j][r] + bv;
        if (relu) v = fmaxf(v, 0.f);
        size_t off = (size_t)(row0 + r) * N + col;
        if (obf) Cb[off] = f2b(v);
        else     Cf[off] = v;
      }
    }
  }
}

// ============================================================
// fp32 GEMM (kept for decoder N=1000 only)
// ============================================================
__global__ __launch_bounds__(256) void gemm_kernel(
    const float* __restrict__ A, const float* __restrict__ W,
    const float* __restrict__ bias, float* __restrict__ C,
    int M, int N, int K, int lda, int relu) {
  __shared__ float As[16][65];
  __shared__ float Ws[16][65];
  int tid = threadIdx.x;
  int bm = blockIdx.y * 64, bn = blockIdx.x * 64;
  int tx = tid & 15, ty = tid >> 4;
  float acc[4][4] = {};
  for (int k0 = 0; k0 < K; k0 += 16) {
    #pragma unroll
    for (int i = 0; i < 4; i++) {
      int idx = i * 256 + tid;
      int r = idx >> 4, c = idx & 15;
      int gr = bm + r;
      As[c][r] = (gr < M) ? A[(size_t)gr * lda + k0 + c] : 0.f;
    }
    #pragma unroll
    for (int i = 0; i < 4; i++) {
      int idx = i * 256 + tid;
      int r = idx >> 6, c = idx & 63;
      int gc = bn + c;
      Ws[r][c] = (gc < N) ? W[(size_t)(k0 + r) * N + gc] : 0.f;
    }
    __syncthreads();
    #pragma unroll
    for (int kk = 0; kk < 16; kk++) {
      float a[4], wv[4];
      #pragma unroll
      for (int i = 0; i < 4; i++) a[i] = As[kk][ty * 4 + i];
      #pragma unroll
      for (int j = 0; j < 4; j++) wv[j] = Ws[kk][tx * 4 + j];
      #pragma unroll
      for (int i = 0; i < 4; i++)
        #pragma unroll
        for (int j = 0; j < 4; j++) acc[i][j] += a[i] * wv[j];
    }
    __syncthreads();
  }
  #pragma unroll
  for (int i = 0; i < 4; i++) {
    int gr = bm + ty * 4 + i;
    if (gr >= M) continue;
    #pragma unroll
    for (int j = 0; j < 4; j++) {
      int gc = bn + tx * 4 + j;
      if (gc >= N) continue;
      float v = acc[i][j];
      if (bias) v += bias[gc];
      if (relu) v = fmaxf(v, 0.f);
      C[(size_t)gr * N + gc] = v;
    }
  }
}

// ============================================================
// Transpose + fp32->bf16: in [K][N] fp32 -> out [N][K] bf16 (batched z)
// ============================================================
__global__ __launch_bounds__(256) void transpose_cvt(
    const float* __restrict__ in, u16* __restrict__ out, int K, int N) {
  __shared__ float tile[32][33];
  int bz = blockIdx.z;
  in  += (size_t)bz * K * N;
  out += (size_t)bz * K * N;
  int n0 = blockIdx.x * 32, k0 = blockIdx.y * 32;
  int tx = threadIdx.x & 31, ty = threadIdx.x >> 5;
  #pragma unroll
  for (int i = 0; i < 4; i++)
    tile[ty + i * 8][tx] = in[(size_t)(k0 + ty + i * 8) * N + n0 + tx];
  __syncthreads();
  #pragma unroll
  for (int i = 0; i < 4; i++)
    out[(size_t)(n0 + ty + i * 8) * K + k0 + tx] = f2b(tile[tx][ty + i * 8]);
}

__global__ __launch_bounds__(256) void zero_u32(u32* __restrict__ p, size_t n) {
  size_t i = (size_t)blockIdx.x * 256 + threadIdx.x;
  if (i < n) p[i] = 0u;
}

// ============================================================
// Patch embed + cls + pos:  h fp32 AND hb bf16
// ============================================================
__global__ __launch_bounds__(256) void patch_kernel(
    const float* __restrict__ x, const float* __restrict__ pw,
    const float* __restrict__ pb, const float* __restrict__ cls,
    const float* __restrict__ pos, float* __restrict__ h, u16* __restrict__ hb) {
  size_t tid = (size_t)blockIdx.x * 256 + threadIdx.x;
  const size_t total = (size_t)NBATCH * SEQL * DEM;
  if (tid >= total) return;
  int d = (int)(tid % DEM);
  int t = (int)((tid / DEM) % SEQL);
  int b = (int)(tid / ((size_t)DEM * SEQL));
  float v;
  if (t == 0) {
    v = cls[d] + pos[d];
  } else {
    int tt = t - 1, pi = tt >> 3, pj = tt & 7;
    float acc = pb[d];
    const float* xb = x + (size_t)b * 3072;
    #pragma unroll
    for (int ch = 0; ch < 3; ch++)
      #pragma unroll
      for (int r = 0; r < 4; r++)
        #pragma unroll
        for (int s = 0; s < 4; s++)
          acc += xb[ch * 1024 + (pi * 4 + r) * 32 + (pj * 4 + s)]
               * pw[(size_t)(ch * 16 + r * 4 + s) * DEM + d];
    v = acc + pos[(size_t)t * DEM + d];
  }
  h[tid] = v;
  hb[tid] = f2b(v);
}

// ============================================================
// MFMA attention: one block (5 waves, 320 thr) per (b, head).
// qkv bf16 [B*T,2304]; out bf16 [B*T,768].
// Tokens padded 65->80 (rows) / ->96 (P contraction).
// ============================================================
#define SP 72    // Q/K LDS row stride (bf16)
#define VP 104   // Vt / Ps row stride (bf16)
__global__ __launch_bounds__(320) void attn_mfma(
    const u16* __restrict__ qkv, u16* __restrict__ out) {
  __shared__ u16 Qs[80 * SP];
  __shared__ u16 Ks[80 * SP];
  __shared__ u16 Vt[64 * VP];
  __shared__ u16 Ps[80 * VP];
  int bh = blockIdx.x;
  int b = bh / NHEAD, hh = bh % NHEAD;
  int tid = threadIdx.x;
  int lane = tid & 63, w = tid >> 6;
  const size_t base = (size_t)b * SEQL * 2304 + hh * HDIM;

  // load Q,K rows (vector 8), zero pad rows
  for (int idx = tid; idx < 65 * 8; idx += 320) {
    int r = idx >> 3, c = (idx & 7) * 8;
    const u16* src = qkv + base + (size_t)r * 2304 + c;
    *(uint4*)&Qs[r * SP + c] = *(const uint4*)src;
    *(uint4*)&Ks[r * SP + c] = *(const uint4*)(src + DEM);
  }
  for (int idx = tid; idx < 15 * 8; idx += 320) {
    int r = 65 + (idx >> 3), c = (idx & 7) * 8;
    uint4 zz = make_uint4(0, 0, 0, 0);
    *(uint4*)&Qs[r * SP + c] = zz;
    *(uint4*)&Ks[r * SP + c] = zz;
  }
  // V transposed into Vt[d][t]
  for (int idx = tid; idx < 65 * 64; idx += 320) {
    int t = idx >> 6, d = idx & 63;
    Vt[d * VP + t] = qkv[base + (size_t)t * 2304 + 2 * DEM + d];
  }
  for (int idx = tid; idx < 64 * 31; idx += 320) {   // zero t in [65,96)
    int d = idx / 31, t = 65 + idx % 31;
    Vt[d * VP + t] = 0;
  }
  for (int idx = tid; idx < 80 * 16; idx += 320) {   // zero Ps t in [80,96)
    int q = idx >> 4, t = 80 + (idx & 15);
    Ps[q * VP + t] = 0;
  }
  __syncthreads();

  const int qm = w * 16;
  const int fr = lane & 15;          // frag row (A) / col (B,C)
  const int fc = (lane >> 4) * 8;    // k-chunk base
  const int qrow = (lane >> 4) * 4;  // C-layout row base

  // ---- QK^T ----
  bf16x8 aq0 = *(const bf16x8*)&Qs[(qm + fr) * SP + fc];
  bf16x8 aq1 = *(const bf16x8*)&Qs[(qm + fr) * SP + 32 + fc];
  f32x4 sacc[5];
  #pragma unroll
  for (int kt = 0; kt < 5; kt++) {
    bf16x8 bk0 = *(const bf16x8*)&Ks[(kt * 16 + fr) * SP + fc];
    bf16x8 bk1 = *(const bf16x8*)&Ks[(kt * 16 + fr) * SP + 32 + fc];
    f32x4 a = (f32x4){0.f, 0.f, 0.f, 0.f};
    a = __builtin_amdgcn_mfma_f32_16x16x32_bf16(aq0, bk0, a, 0, 0, 0);
    a = __builtin_amdgcn_mfma_f32_16x16x32_bf16(aq1, bk1, a, 0, 0, 0);
    sacc[kt] = a;
  }

  // ---- softmax over cols (register + shfl within 16-lane groups) ----
  #pragma unroll
  for (int r = 0; r < 4; r++) {
    float v[5];
    float mx = -1e30f;
    #pragma unroll
    for (int kt = 0; kt < 5; kt++) {
      int col = kt * 16 + fr;
      float t = sacc[kt][r] * 0.125f;
      bool valid = (col < SEQL);
      v[kt] = valid ? t : -1e30f;
      mx = fmaxf(mx, v[kt]);
    }
    #pragma unroll
    for (int off = 1; off < 16; off <<= 1) mx = fmaxf(mx, __shfl_xor(mx, off, 64));
    float sum = 0.f;
    #pragma unroll
    for (int kt = 0; kt < 5; kt++) {
      float e = (v[kt] > -1e29f) ? __expf(v[kt] - mx) : 0.f;
      v[kt] = e;
      sum += e;
    }
    #pragma unroll
    for (int off = 1; off < 16; off <<= 1) sum += __shfl_xor(sum, off, 64);
    float inv = 1.f / sum;
    #pragma unroll
    for (int kt = 0; kt < 5; kt++)
      Ps[(qm + qrow + r) * VP + kt * 16 + fr] = f2b(v[kt] * inv);
  }
  // wave-local LDS write->read (rows owned by this wave); lockstep wave, no barrier

  // ---- PV ----
  bf16x8 ap[3];
  #pragma unroll
  for (int c = 0; c < 3; c++)
    ap[c] = *(const bf16x8*)&Ps[(qm + fr) * VP + c * 32 + fc];
  #pragma unroll
  for (int dt = 0; dt < 4; dt++) {
    f32x4 vac = (f32x4){0.f, 0.f, 0.f, 0.f};
    #pragma unroll
    for (int c = 0; c < 3; c++) {
      bf16x8 bv = *(const bf16x8*)&Vt[(dt * 16 + fr) * VP + c * 32 + fc];
      vac = __builtin_amdgcn_mfma_f32_16x16x32_bf16(ap[c], bv, vac, 0, 0, 0);
    }
    int q0 = qm + qrow, d = dt * 16 + fr;
    #pragma unroll
    for (int r = 0; r < 4; r++) {
      int q = q0 + r;
      if (q < SEQL)
        out[((size_t)b * SEQL + q) * DEM + hh * HDIM + d] = f2b(vac[r]);
    }
  }
}

// ============================================================
// h = LayerNorm(h + f); writes fp32 h and bf16 hb
// ============================================================
__global__ __launch_bounds__(256) void add_ln_kernel(
    float* __restrict__ h, const float* __restrict__ f,
    const float* __restrict__ g, const float* __restrict__ b,
    u16* __restrict__ hb) {
  int t = blockIdx.x, tid = threadIdx.x;
  float* hr = h + (size_t)t * DEM;
  u16* hbr = hb + (size_t)t * DEM;
  const float* fr = f + (size_t)t * DEM;
  float x[3];
  float s = 0.f;
  #pragma unroll
  for (int i = 0; i < 3; i++) { x[i] = hr[tid + i * 256] + fr[tid + i * 256]; s += x[i]; }
  __shared__ float red[256];
  red[tid] = s; __syncthreads();
  for (int o = 128; o > 0; o >>= 1) { if (tid < o) red[tid] += red[tid + o]; __syncthreads(); }
  float mean = red[0] / (float)DEM;
  __syncthreads();
  float vs = 0.f;
  #pragma unroll
  for (int i = 0; i < 3; i++) { float d = x[i] - mean; vs += d * d; }
  red[tid] = vs; __syncthreads();
  for (int o = 128; o > 0; o >>= 1) { if (tid < o) red[tid] += red[tid + o]; __syncthreads(); }
  float var = red[0] / (float)DEM;
  float rstd = rsqrtf(var + 1e-5f);
  #pragma unroll
  for (int i = 0; i < 3; i++) {
    int d = tid + i * 256;
    float v = (x[i] - mean) * rstd * g[d] + b[d];
    hr[d] = v;
    hbr[d] = f2b(v);
  }
}

// ============================================================
// Gate logits: logits[S,8] = h[S,768] @ gw[768,8] (fp32, exact routing)
// block = 32 tokens x 8 experts
// ============================================================
__global__ __launch_bounds__(256) void gate_logits(
    const float* __restrict__ h, const float* __restrict__ gw,
    float* __restrict__ glog) {
  __shared__ float wg[DEM * NEXP];
  int tid = threadIdx.x;
  for (int i = tid; i < DEM * NEXP; i += 256) wg[i] = gw[i];
  __syncthreads();
  int token = blockIdx.x * 32 + (tid >> 3), e = tid & 7;
  const float* hr = h + (size_t)token * DEM;
  float s = 0.f;
  for (int d = 0; d < DEM; d += 4) {
    s += hr[d]     * wg[d * 8 + e]
       + hr[d + 1] * wg[(d + 1) * 8 + e]
       + hr[d + 2] * wg[(d + 2) * 8 + e]
       + hr[d + 3] * wg[(d + 3) * 8 + e];
  }
  glog[(size_t)token * NEXP + e] = s;
}

// ============================================================
// Gate phase A + per-block expert counts. grid = 65 blocks x 256.
// ============================================================
__global__ __launch_bounds__(256) void moe_gate_a(
    const float* __restrict__ logits, int* __restrict__ e1, int* __restrict__ e2,
    float* __restrict__ gv1, float* __restrict__ gv2,
    int* __restrict__ cnt1, int* __restrict__ cnt2) {
  __shared__ int c1s[NEXP], c2s[NEXP];
  int tid = threadIdx.x;
  int s = blockIdx.x * 256 + tid;
  if (tid < NEXP) { c1s[tid] = 0; c2s[tid] = 0; }
  __syncthreads();
  const float* l = logits + (size_t)s * NEXP;
  float lv[NEXP];
  #pragma unroll
  for (int e = 0; e < NEXP; e++) lv[e] = l[e];
  float mx = lv[0];
  #pragma unroll
  for (int e = 1; e < NEXP; e++) mx = fmaxf(mx, lv[e]);
  float g[NEXP]; float sum = 0.f;
  #pragma unroll
  for (int e = 0; e < NEXP; e++) { g[e] = __expf(lv[e] - mx); sum += g[e]; }
  float inv = 1.f / sum;
  int b1 = 0; float bv = lv[0];
  #pragma unroll
  for (int e = 1; e < NEXP; e++) if (lv[e] > bv) { bv = lv[e]; b1 = e; }  // first max
  int b2 = -1; float bv2 = -1e30f;
  #pragma unroll
  for (int e = 0; e < NEXP; e++) if (e != b1 && lv[e] > bv2) { bv2 = lv[e]; b2 = e; }
  e1[s] = b1; e2[s] = b2;
  gv1[s] = g[b1] * inv; gv2[s] = g[b2] * inv;
  atomicAdd(&c1s[b1], 1);
  atomicAdd(&c2s[b2], 1);
  __syncthreads();
  if (tid < NEXP) {
    cnt1[blockIdx.x * NEXP + tid] = c1s[tid];
    cnt2[blockIdx.x * NEXP + tid] = c2s[tid];
  }
}

// exclusive prefix over 65 blocks per expert; base2 continues from total1
__global__ __launch_bounds__(64) void moe_base(
    const int* __restrict__ cnt1, const int* __restrict__ cnt2,
    int* __restrict__ base1, int* __restrict__ base2) {
  int e = threadIdx.x;
  if (e >= NEXP) return;
  int run = 0;
  for (int b = 0; b < 65; b++) { base1[b * NEXP + e] = run; run += cnt1[b * NEXP + e]; }
  for (int b = 0; b < 65; b++) { base2[b * NEXP + e] = run; run += cnt2[b * NEXP + e]; }
}

// per-block ballot ranking + capacity/renorm. grid = 65 x 256.
__global__ __launch_bounds__(256) void moe_rank(
    const int* __restrict__ e1, const int* __restrict__ e2,
    const int* __restrict__ base1, const int* __restrict__ base2,
    const float* __restrict__ gv1, const float* __restrict__ gv2,
    int* __restrict__ sl1, int* __restrict__ sl2,
    int* __restrict__ k1, int* __restrict__ k2,
    float* __restrict__ g1, float* __restrict__ g2) {
  int blk = blockIdx.x, tid = threadIdx.x;
  int s = blk * 256 + tid;
  int lane = tid & 63, w = tid >> 6;
  __shared__ int wsum[4][NEXP];
  int my1 = e1[s], my2 = e2[s];
  unsigned long long mymask = 0;
  #pragma unroll
  for (int e = 0; e < NEXP; e++) {
    unsigned long long m = __ballot(my1 == e);
    if (my1 == e) mymask = m;
    if (lane == e) wsum[w][e] = __popcll(m);
  }
  int rank = __popcll(mymask & ((1ull << lane) - 1ull));
  __syncthreads();
  int off = 0;
  for (int ww = 0; ww < w; ww++) off += wsum[ww][my1];
  int P1 = base1[blk * NEXP + my1] + off + rank;
  __syncthreads();
  mymask = 0;
  #pragma unroll
  for (int e = 0; e < NEXP; e++) {
    unsigned long long m = __ballot(my2 == e);
    if (my2 == e) mymask = m;
    if (lane == e) wsum[w][e] = __popcll(m);
  }
  rank = __popcll(mymask & ((1ull << lane) - 1ull));
  __syncthreads();
  off = 0;
  for (int ww = 0; ww < w; ww++) off += wsum[ww][my2];
  int P2 = base2[blk * NEXP + my2] + off + rank;

  int K1 = (P1 < CAPC) ? 1 : 0, K2 = (P2 < CAPC) ? 1 : 0;
  float G1 = gv1[s] * (float)K1, G2 = gv2[s] * (float)K2;
  float denom = fmaxf(G1 + G2, 1e-9f);
  g1[s] = G1 / denom; g2[s] = G2 / denom;
  int c1 = P1 < CAPC - 1 ? P1 : CAPC - 1;
  int c2 = P2 < CAPC - 1 ? P2 : CAPC - 1;
  sl1[s] = my1 * CAPP + c1;
  sl2[s] = my2 * CAPP + c2;
  k1[s] = K1; k2[s] = K2;
}

__global__ __launch_bounds__(256) void moe_scatter(
    const u16* __restrict__ hb, const int* __restrict__ slot1,
    const int* __restrict__ slot2, const int* __restrict__ k1,
    const int* __restrict__ k2, u16* __restrict__ ebuf) {
  int s = blockIdx.x, tid = threadIdx.x;
  const u16* hr = hb + (size_t)s * DEM;
  int s1 = slot1[s], s2 = slot2[s], K1 = k1[s], K2 = k2[s];
  #pragma unroll
  for (int i = 0; i < 3; i++) {
    int d = tid + i * 256;
    u16 v = hr[d];
    if (K1) ebuf[(size_t)s1 * DEM + d] = v;
    if (K2) ebuf[(size_t)s2 * DEM + d] = v;
  }
}

__global__ __launch_bounds__(256) void moe_combine(
    const float* __restrict__ oe, const int* __restrict__ slot1,
    const int* __restrict__ slot2, const float* __restrict__ g1,
    const float* __restrict__ g2, float* __restrict__ out) {
  int s = blockIdx.x, tid = threadIdx.x;
  int s1 = slot1[s], s2 = slot2[s];
  float G1 = g1[s], G2 = g2[s];
  #pragma unroll
  for (int i = 0; i < 3; i++) {
    int d = tid + i * 256;
    out[(size_t)s * DEM + d] = oe[(size_t)s1 * DEM + d] * G1 + oe[(size_t)s2 * DEM + d] * G2;
  }
}

// ============================================================
// Loss
// ============================================================
__global__ __launch_bounds__(256) void loss_kernel(
    const float* __restrict__ logits, const int* __restrict__ y,
    float* __restrict__ losses) {
  int b = blockIdx.x, tid = threadIdx.x;
  const float* l = logits + (size_t)b * NCLS;
  __shared__ float red[256];
  float mx = -1e30f;
  for (int c = tid; c < NCLS; c += 256) mx = fmaxf(mx, l[c]);
  red[tid] = mx; __syncthreads();
  for (int o = 128; o > 0; o >>= 1) { if (tid < o) red[tid] = fmaxf(red[tid], red[tid + o]); __syncthreads(); }
  mx = red[0]; __syncthreads();
  float s = 0.f;
  for (int c = tid; c < NCLS; c += 256) s += __expf(l[c] - mx);
  red[tid] = s; __syncthreads();
  for (int o = 128; o > 0; o >>= 1) { if (tid < o) red[tid] += red[tid + o]; __syncthreads(); }
  if (tid == 0) losses[b] = logf(red[0]) + mx - l[y[b]];
}

__global__ __launch_bounds__(256) void loss_reduce(
    const float* __restrict__ losses, float* __restrict__ out) {
  __shared__ float red[256];
  int tid = threadIdx.x;
  red[tid] = losses[tid]; __syncthreads();
  for (int o = 128; o > 0; o >>= 1) { if (tid < o) red[tid] += red[tid + o]; __syncthreads(); }
  if (tid == 0) out[0] = red[0];
}

// ============================================================
// Host orchestration
// ============================================================
extern "C" void kernel_launch(void* const* d_in, const int* in_sizes, int n_in,
                              void* d_out, int out_size, void* d_ws, size_t ws_size,
                              hipStream_t stream) {
  const float* x       = (const float*)d_in[0];
  const int*   y       = (const int*)  d_in[1];
  const float* patch_w = (const float*)d_in[2];
  const float* patch_b = (const float*)d_in[3];
  const float* cls     = (const float*)d_in[4];
  const float* pos     = (const float*)d_in[5];
  const float* wqkv    = (const float*)d_in[6];
  const float* bqkv    = (const float*)d_in[7];
  const float* wo      = (const float*)d_in[8];
  const float* bo      = (const float*)d_in[9];
  const float* ln1g    = (const float*)d_in[10];
  const float* ln1b    = (const float*)d_in[11];
  const float* ln2g    = (const float*)d_in[12];
  const float* ln2b    = (const float*)d_in[13];
  const float* dw1     = (const float*)d_in[14];
  const float* db1     = (const float*)d_in[15];
  const float* dw2     = (const float*)d_in[16];
  const float* db2     = (const float*)d_in[17];
  const float* gate_w  = (const float*)d_in[18];
  const float* ew1     = (const float*)d_in[19];
  const float* eb1     = (const float*)d_in[20];
  const float* ew2     = (const float*)d_in[21];
  const float* eb2     = (const float*)d_in[22];
  const float* dec_w   = (const float*)d_in[23];
  const float* dec_b   = (const float*)d_in[24];
  float* out = (float*)d_out;

  // ---- workspace layout ----
  char* cur = (char*)d_ws;
  auto alloc = [&](size_t bytes) -> char* {
    char* p = cur;
    cur += (bytes + 255) & ~(size_t)255;
    return p;
  };
  float* h    = (float*)alloc((size_t)STOK * DEM * 4);
  float* big1 = (float*)alloc((size_t)STOK * DEM * 4);
  float* oe   = (float*)alloc((size_t)NEXP * CAPP * DEM * 4);
  float* glog = (float*)alloc((size_t)STOK * NEXP * 4);
  float* gv1  = (float*)alloc((size_t)STOK * 4);
  float* gv2  = (float*)alloc((size_t)STOK * 4);
  float* g1   = (float*)alloc((size_t)STOK * 4);
  float* g2   = (float*)alloc((size_t)STOK * 4);
  float* losses = (float*)alloc(256 * 4);
  int* e1v = (int*)alloc((size_t)STOK * 4);
  int* e2v = (int*)alloc((size_t)STOK * 4);
  int* sl1 = (int*)alloc((size_t)STOK * 4);
  int* sl2 = (int*)alloc((size_t)STOK * 4);
  int* k1v = (int*)alloc((size_t)STOK * 4);
  int* k2v = (int*)alloc((size_t)STOK * 4);
  int* cnt1 = (int*)alloc(65 * NEXP * 4);
  int* cnt2 = (int*)alloc(65 * NEXP * 4);
  int* bas1 = (int*)alloc(65 * NEXP * 4);
  int* bas2 = (int*)alloc(65 * NEXP * 4);
  u16* hb   = (u16*)alloc((size_t)STOK * DEM * 2);
  u16* ab   = (u16*)alloc((size_t)STOK * DEM * 2);
  u16* ubuf = (u16*)alloc((size_t)NEXP * CAPP * NHID * 2);
  u16* wt   = (u16*)alloc((size_t)NEXP * NHID * DEM * 2);
  u16* ebuf = (u16*)alloc((size_t)NEXP * CAPP * DEM * 2);

  auto gemmM = [&](const u16* A, size_t sA, const u16* W, size_t sW,
                   const float* bias, size_t sB, void* C, size_t sC,
                   int M, int N, int K, int relu, int obf, int batch) {
    dim3 grid(N / 128, M / 128, batch);
    gemm_bf16<<<grid, 256, 0, stream>>>(A, sA, W, sW, bias, sB, C, sC, M, N, K, relu, obf);
  };
  auto trans = [&](const float* in, u16* o, int K, int N, int batch) {
    dim3 grid(N / 32, K / 32, batch);
    transpose_cvt<<<grid, 256, 0, stream>>>(in, o, K, N);
  };

  // patch embed (writes h + hb)
  {
    size_t total = (size_t)NBATCH * SEQL * DEM;
    patch_kernel<<<(unsigned)((total + 255) / 256), 256, 0, stream>>>(
        x, patch_w, patch_b, cls, pos, h, hb);
  }

  int di = 0, mi = 0;
  for (int i = 0; i < NLAY; i++) {
    // ---- MHA ----
    trans(wqkv + (size_t)i * DEM * 3 * DEM, wt, DEM, 3 * DEM, 1);
    gemmM(hb, 0, wt, 0, bqkv + (size_t)i * 3 * DEM, 0, ubuf, 0,
          STOK, 3 * DEM, DEM, 0, 1, 1);
    attn_mfma<<<NBATCH * NHEAD, 320, 0, stream>>>(ubuf, ab);
    trans(wo + (size_t)i * DEM * DEM, wt, DEM, DEM, 1);
    gemmM(ab, 0, wt, 0, bo + (size_t)i * DEM, 0, big1, 0,
          STOK, DEM, DEM, 0, 0, 1);
    add_ln_kernel<<<STOK, 256, 0, stream>>>(h, big1, ln1g + (size_t)i * DEM,
                                            ln1b + (size_t)i * DEM, hb);

    if (i % 2 == 0) {
      // ---- dense FFN ----
      trans(dw1 + (size_t)di * DEM * NHID, wt, DEM, NHID, 1);
      gemmM(hb, 0, wt, 0, db1 + (size_t)di * NHID, 0, ubuf, 0,
            STOK, NHID, DEM, 1, 1, 1);
      trans(dw2 + (size_t)di * NHID * DEM, wt, NHID, DEM, 1);
      gemmM(ubuf, 0, wt, 0, db2 + (size_t)di * DEM, 0, big1, 0,
            STOK, DEM, NHID, 0, 0, 1);
      di++;
    } else {
      // ---- MoE FFN ----
      gate_logits<<<STOK / 32, 256, 0, stream>>>(h, gate_w + (size_t)mi * DEM * NEXP, glog);
      moe_gate_a<<<65, 256, 0, stream>>>(glog, e1v, e2v, gv1, gv2, cnt1, cnt2);
      moe_base<<<1, 64, 0, stream>>>(cnt1, cnt2, bas1, bas2);
      moe_rank<<<65, 256, 0, stream>>>(e1v, e2v, bas1, bas2, gv1, gv2,
                                       sl1, sl2, k1v, k2v, g1, g2);
      {
        size_t nz = (size_t)NEXP * CAPP * DEM / 2;
        zero_u32<<<(unsigned)((nz + 255) / 256), 256, 0, stream>>>((u32*)ebuf, nz);
      }
      moe_scatter<<<STOK, 256, 0, stream>>>(hb, sl1, sl2, k1v, k2v, ebuf);
      trans(ew1 + (size_t)mi * NEXP * DEM * NHID, wt, DEM, NHID, NEXP);
      gemmM(ebuf, (size_t)CAPP * DEM, wt, (size_t)NHID * DEM,
            eb1 + (size_t)mi * NEXP * NHID, NHID, ubuf, (size_t)CAPP * NHID,
            CAPP, NHID, DEM, 1, 1, NEXP);
      trans(ew2 + (size_t)mi * NEXP * NHID * DEM, wt, NHID, DEM, NEXP);
      gemmM(ubuf, (size_t)CAPP * NHID, wt, (size_t)DEM * NHID,
            eb2 + (size_t)mi * NEXP * DEM, DEM, oe, (size_t)CAPP * DEM,
            CAPP, DEM, NHID, 0, 0, NEXP);
      moe_combine<<<STOK, 256, 0, stream>>>(oe, sl1, sl2, g1, g2, big1);
      mi++;
    }
    add_ln_kernel<<<STOK, 256, 0, stream>>>(h, big1, ln2g + (size_t)i * DEM,
                                            ln2b + (size_t)i * DEM, hb);
  }

  // decoder on CLS tokens + loss (oe reused for logits)
  {
    dim3 grid((NCLS + 63) / 64, (NBATCH + 63) / 64);
    gemm_kernel<<<grid, 256, 0, stream>>>(h, dec_w, dec_b, oe,
                                          NBATCH, NCLS, DEM, SEQL * DEM, 0);
  }
  loss_kernel<<<NBATCH, 256, 0, stream>>>(oe, y, losses);
  loss_reduce<<<1, 256, 0, stream>>>(losses, out);
}